// Round 1
// baseline (1246.741 us; speedup 1.0000x reference)
//
#include <hip/hip_runtime.h>
#include <hip/hip_bf16.h>
#include <cstdint>
#include <cstddef>

// ActorHead fused pipeline, bf16 MFMA throughout.
//   K1 k_qkv : [4096x1536x512] GEMM-BT -> Qb (scaled), Kb, Vt (per-head transposed), all bf16
//   K2 k_attn: flash attention w/ dual online softmax (scores + bias) + influence cross-term
//   K3 k_fold: fold out_w over heads (topic = ctx @ mean_h(out_w chunks)^T)
//   K4 k_out : [4096x128x512] GEMM -> topic (valid-gated)
// d_out = topic[4096*128] fp32 ++ influence[4096] fp32

typedef __attribute__((ext_vector_type(8))) short bf16x8;
typedef __attribute__((ext_vector_type(4))) short bf16x4;
typedef __attribute__((ext_vector_type(4))) float f32x4;

#define MFMA_BF16(a, b, c) __builtin_amdgcn_mfma_f32_16x16x32_bf16((a), (b), (c), 0, 0, 0)

static __device__ __forceinline__ short f2b(float x) {
  union { float f; unsigned u; } v; v.f = x;
  unsigned r = v.u + 0x7fffu + ((v.u >> 16) & 1u);  // RNE to bf16
  return (short)(r >> 16);
}

// ---------------- K1: QKV projection ----------------
// C[4096 x 1536] = A[4096 x 512] @ W[1536 x 512]^T + b, A = a_z (cols<512) else bv_z.
// Epilogue: cols 0-511 -> Qb (x 1/sqrt(128)); 512-1023 -> Kb; 1024-1535 -> Vt[h*128+d][m].
__global__ __launch_bounds__(256) void k_qkv(
    const float* __restrict__ a, const float* __restrict__ kv,
    const float* __restrict__ w, const float* __restrict__ bias,
    short* __restrict__ Qb, short* __restrict__ Kb, short* __restrict__ Vt)
{
  __shared__ short As[128 * 40];  // +8 pad: conflict-uniform b128 frag reads
  __shared__ short Bs[128 * 40];
  const int blk = blockIdx.x;
  const int bm = blk / 12, bn = blk % 12;
  const int m0 = bm * 128, n0 = bn * 128;
  const float* __restrict__ Ain = (bn < 4) ? a : kv;
  const int tid = threadIdx.x;
  const int lane = tid & 63, wv = tid >> 6;
  const int wm = (wv >> 1) * 64, wn = (wv & 1) * 64;
  const int c = lane & 15, g = lane >> 4;
  const int srow = tid >> 1, scol = (tid & 1) * 16;

  f32x4 acc[4][4];
#pragma unroll
  for (int i = 0; i < 4; ++i)
#pragma unroll
    for (int j = 0; j < 4; ++j) acc[i][j] = (f32x4)0.f;

  for (int k0 = 0; k0 < 512; k0 += 32) {
    const float* ap = Ain + (size_t)(m0 + srow) * 512 + k0 + scol;
    const float* bp = w + (size_t)(n0 + srow) * 512 + k0 + scol;
#pragma unroll
    for (int j = 0; j < 4; ++j) {
      f32x4 av = *(const f32x4*)(ap + 4 * j);
      f32x4 bv = *(const f32x4*)(bp + 4 * j);
      bf16x4 as, bs;
      as.x = f2b(av.x); as.y = f2b(av.y); as.z = f2b(av.z); as.w = f2b(av.w);
      bs.x = f2b(bv.x); bs.y = f2b(bv.y); bs.z = f2b(bv.z); bs.w = f2b(bv.w);
      *(bf16x4*)(&As[srow * 40 + scol + 4 * j]) = as;
      *(bf16x4*)(&Bs[srow * 40 + scol + 4 * j]) = bs;
    }
    __syncthreads();
    bf16x8 af[4], bfg[4];
#pragma unroll
    for (int t = 0; t < 4; ++t) {
      af[t]  = *(const bf16x8*)(&As[(wm + t * 16 + c) * 40 + g * 8]);
      bfg[t] = *(const bf16x8*)(&Bs[(wn + t * 16 + c) * 40 + g * 8]);
    }
#pragma unroll
    for (int rt = 0; rt < 4; ++rt)
#pragma unroll
      for (int ct = 0; ct < 4; ++ct)
        acc[rt][ct] = MFMA_BF16(af[rt], bfg[ct], acc[rt][ct]);
    __syncthreads();
  }

#pragma unroll
  for (int ct = 0; ct < 4; ++ct) {
    const int col = n0 + wn + ct * 16 + c;
    const float bj = bias[col];
#pragma unroll
    for (int rt = 0; rt < 4; ++rt) {
      const int row = m0 + wm + rt * 16 + g * 4;
      if (bn < 4) {
#pragma unroll
        for (int r = 0; r < 4; ++r)
          Qb[(size_t)(row + r) * 512 + col] = f2b((acc[rt][ct][r] + bj) * 0.08838834764831843f);
      } else if (bn < 8) {
#pragma unroll
        for (int r = 0; r < 4; ++r)
          Kb[(size_t)(row + r) * 512 + (col - 512)] = f2b(acc[rt][ct][r] + bj);
      } else {
        bf16x4 pk;
#pragma unroll
        for (int r = 0; r < 4; ++r) pk[r] = f2b(acc[rt][ct][r] + bj);
        *(bf16x4*)(&Vt[(size_t)(col - 1024) * 4096 + row]) = pk;  // V transposed per head-dim
      }
    }
  }
}

// ---------------- K2: fused flash attention + influence ----------------
// One wg = 32 actor rows; wave = head. BT=64 keys/iter. Dual online softmax.
__global__ __launch_bounds__(256, 1) void k_attn(
    const short* __restrict__ Qb, const short* __restrict__ Kb,
    const short* __restrict__ Vt, const float* __restrict__ wgt,
    const int* __restrict__ msk, short* __restrict__ ctxb,
    float* __restrict__ validw, float* __restrict__ infl)
{
  __shared__ short Pbuf[4][32 * 72];  // per-wave P round-trip (C-layout -> A-layout)
  __shared__ float Ipart[4][32];
  __shared__ float LbS[32];
  __shared__ float VaS[32];

  const int n0 = blockIdx.x * 32;
  const int tid = threadIdx.x;
  const int lane = tid & 63, h = tid >> 6;
  const int c = lane & 15, g = lane >> 4;

  // Q A-frags, direct from global in MFMA layout (row=c, kchunk=g*8)
  bf16x8 qf[2][4];
#pragma unroll
  for (int nb = 0; nb < 2; ++nb)
#pragma unroll
    for (int ks = 0; ks < 4; ++ks)
      qf[nb][ks] = *(const bf16x8*)(Qb + (size_t)(n0 + nb * 16 + c) * 512 + h * 128 + ks * 32 + g * 8);

  f32x4 O[2][8];
#pragma unroll
  for (int nb = 0; nb < 2; ++nb)
#pragma unroll
    for (int db = 0; db < 8; ++db) O[nb][db] = (f32x4)0.f;

  float mh[2][4], lh[2][4], mb_[2][4], lb_[2][4], ci[2][4], va[2][4];
#pragma unroll
  for (int nb = 0; nb < 2; ++nb)
#pragma unroll
    for (int r = 0; r < 4; ++r) {
      mh[nb][r] = -1e30f; lh[nb][r] = 0.f;
      mb_[nb][r] = -1e30f; lb_[nb][r] = 0.f;
      ci[nb][r] = 0.f; va[nb][r] = 0.f;
    }

  for (int m0 = 0; m0 < 4096; m0 += 64) {
    // ---- scores S = q @ k^T (C-layout: row=n=g*4+reg, col=m=c) ----
    f32x4 S[2][4];
#pragma unroll
    for (int mb = 0; mb < 4; ++mb) {
      bf16x8 kf[4];
#pragma unroll
      for (int ks = 0; ks < 4; ++ks)
        kf[ks] = *(const bf16x8*)(Kb + (size_t)(m0 + mb * 16 + c) * 512 + h * 128 + ks * 32 + g * 8);
#pragma unroll
      for (int nb = 0; nb < 2; ++nb) {
        f32x4 s = (f32x4)0.f;
#pragma unroll
        for (int ks = 0; ks < 4; ++ks) s = MFMA_BF16(qf[nb][ks], kf[ks], s);
        S[nb][mb] = s;
      }
    }
    // ---- bias load (mask? w : -1e9) + tile maxima ----
    float bb[2][4][4];
    float tmx[2][4], btm[2][4];
#pragma unroll
    for (int nb = 0; nb < 2; ++nb)
#pragma unroll
      for (int r = 0; r < 4; ++r) { tmx[nb][r] = -1e30f; btm[nb][r] = -1e30f; }
#pragma unroll
    for (int nb = 0; nb < 2; ++nb) {
      const int rbase = n0 + nb * 16 + g * 4;
#pragma unroll
      for (int mb = 0; mb < 4; ++mb) {
        const int colm = m0 + mb * 16 + c;
#pragma unroll
        for (int r = 0; r < 4; ++r) {
          const size_t idx = (size_t)(rbase + r) * 4096 + colm;
          const int mk = msk[idx];
          const float bv = mk ? wgt[idx] : -1e9f;
          bb[nb][mb][r] = bv;
          va[nb][r] = fmaxf(va[nb][r], mk ? 1.f : 0.f);
          const float sc = S[nb][mb][r] + bv;
          S[nb][mb][r] = sc;
          tmx[nb][r] = fmaxf(tmx[nb][r], sc);
          btm[nb][r] = fmaxf(btm[nb][r], bv);
        }
      }
    }
    // ---- cross-lane max within 16-lane col group ----
#pragma unroll
    for (int x = 1; x < 16; x <<= 1)
#pragma unroll
      for (int nb = 0; nb < 2; ++nb)
#pragma unroll
        for (int r = 0; r < 4; ++r) {
          tmx[nb][r] = fmaxf(tmx[nb][r], __shfl_xor(tmx[nb][r], x, 64));
          btm[nb][r] = fmaxf(btm[nb][r], __shfl_xor(btm[nb][r], x, 64));
        }
    // ---- online rescale ----
    float osc[2][4];
#pragma unroll
    for (int nb = 0; nb < 2; ++nb)
#pragma unroll
      for (int r = 0; r < 4; ++r) {
        const float mn = fmaxf(mh[nb][r], tmx[nb][r]);
        const float al = __expf(mh[nb][r] - mn);
        mh[nb][r] = mn;
        const float bmn = fmaxf(mb_[nb][r], btm[nb][r]);
        const float bl = __expf(mb_[nb][r] - bmn);
        mb_[nb][r] = bmn;
        lh[nb][r] *= al; lb_[nb][r] *= bl; ci[nb][r] *= al * bl;
        osc[nb][r] = al;
      }
#pragma unroll
    for (int nb = 0; nb < 2; ++nb)
#pragma unroll
      for (int db = 0; db < 8; ++db)
#pragma unroll
        for (int r = 0; r < 4; ++r) O[nb][db][r] *= osc[nb][r];
    // ---- P = exp(s-mh), eb = exp(b-mb); accumulate l, lb, cross-term ----
#pragma unroll
    for (int nb = 0; nb < 2; ++nb)
#pragma unroll
      for (int mb = 0; mb < 4; ++mb)
#pragma unroll
        for (int r = 0; r < 4; ++r) {
          const float p  = __expf(S[nb][mb][r] - mh[nb][r]);
          const float eb = __expf(bb[nb][mb][r] - mb_[nb][r]);
          lh[nb][r] += p; lb_[nb][r] += eb; ci[nb][r] += p * eb;
          Pbuf[h][(nb * 16 + g * 4 + r) * 72 + mb * 16 + c] = f2b(p);
        }
    // ---- PV: O += P @ V  (A-frags from Pbuf, B-frags from Vt) ----
#pragma unroll
    for (int ks2 = 0; ks2 < 2; ++ks2) {
      bf16x8 pa[2];
#pragma unroll
      for (int nb = 0; nb < 2; ++nb)
        pa[nb] = *(const bf16x8*)(&Pbuf[h][(nb * 16 + c) * 72 + ks2 * 32 + g * 8]);
#pragma unroll
      for (int db = 0; db < 8; ++db) {
        const bf16x8 vf = *(const bf16x8*)(Vt + (size_t)(h * 128 + db * 16 + c) * 4096 + m0 + ks2 * 32 + g * 8);
#pragma unroll
        for (int nb = 0; nb < 2; ++nb) O[nb][db] = MFMA_BF16(pa[nb], vf, O[nb][db]);
      }
    }
  }

  // ---- final cross-lane sums (cols are disjoint across the 16 lanes) ----
#pragma unroll
  for (int x = 1; x < 16; x <<= 1)
#pragma unroll
    for (int nb = 0; nb < 2; ++nb)
#pragma unroll
      for (int r = 0; r < 4; ++r) {
        lh[nb][r] += __shfl_xor(lh[nb][r], x, 64);
        lb_[nb][r] += __shfl_xor(lb_[nb][r], x, 64);
        ci[nb][r] += __shfl_xor(ci[nb][r], x, 64);
        va[nb][r] = fmaxf(va[nb][r], __shfl_xor(va[nb][r], x, 64));
      }

  // ---- ctx out (bf16) ----
#pragma unroll
  for (int nb = 0; nb < 2; ++nb)
#pragma unroll
    for (int db = 0; db < 8; ++db)
#pragma unroll
      for (int r = 0; r < 4; ++r) {
        const float o = O[nb][db][r] / lh[nb][r];
        ctxb[(size_t)(n0 + nb * 16 + g * 4 + r) * 512 + h * 128 + db * 16 + c] = f2b(o);
      }

  // ---- influence combine across heads ----
  if (c == 0) {
#pragma unroll
    for (int nb = 0; nb < 2; ++nb)
#pragma unroll
      for (int r = 0; r < 4; ++r) {
        const int row = nb * 16 + g * 4 + r;
        Ipart[h][row] = ci[nb][r] / lh[nb][r];
        if (h == 0) {
          LbS[row] = lb_[nb][r];
          VaS[row] = va[nb][r];
          validw[n0 + row] = va[nb][r];
        }
      }
  }
  __syncthreads();
  if (tid < 32) {
    const float s = (Ipart[0][tid] + Ipart[1][tid] + Ipart[2][tid] + Ipart[3][tid]) /
                    (4.f * LbS[tid]);
    infl[n0 + tid] = (VaS[tid] > 0.5f) ? s : 0.f;
  }
}

// ---------------- K3: fold out_w over heads ----------------
__global__ void k_fold(const float* __restrict__ ow, const float* __restrict__ ob,
                       short* __restrict__ Wf, float* __restrict__ bfo)
{
  const int idx = blockIdx.x * 256 + threadIdx.x;
  if (idx < 128 * 512) {
    const int dk = idx >> 9, d = idx & 511;
    const float s = 0.25f * (ow[(size_t)dk * 512 + d] + ow[(size_t)(dk + 128) * 512 + d] +
                             ow[(size_t)(dk + 256) * 512 + d] + ow[(size_t)(dk + 384) * 512 + d]);
    Wf[(size_t)dk * 512 + d] = f2b(s);
  }
  if (idx < 128) bfo[idx] = 0.25f * (ob[idx] + ob[idx + 128] + ob[idx + 256] + ob[idx + 384]);
}

// ---------------- K4: topic = ctx @ Wfold^T + bfold, valid-gated ----------------
__global__ __launch_bounds__(256) void k_out(
    const short* __restrict__ ctxb, const short* __restrict__ Wf,
    const float* __restrict__ bfo, const float* __restrict__ validw,
    float* __restrict__ topic)
{
  __shared__ short As[128 * 40];
  __shared__ short Bs[128 * 40];
  const int m0 = blockIdx.x * 128;
  const int tid = threadIdx.x;
  const int lane = tid & 63, wv = tid >> 6;
  const int wm = (wv >> 1) * 64, wn = (wv & 1) * 64;
  const int c = lane & 15, g = lane >> 4;
  const int srow = tid >> 1, scol = (tid & 1) * 16;

  f32x4 acc[4][4];
#pragma unroll
  for (int i = 0; i < 4; ++i)
#pragma unroll
    for (int j = 0; j < 4; ++j) acc[i][j] = (f32x4)0.f;

  for (int k0 = 0; k0 < 512; k0 += 32) {
    const bf16x8 av0 = *(const bf16x8*)(ctxb + (size_t)(m0 + srow) * 512 + k0 + scol);
    const bf16x8 av1 = *(const bf16x8*)(ctxb + (size_t)(m0 + srow) * 512 + k0 + scol + 8);
    const bf16x8 bv0 = *(const bf16x8*)(Wf + (size_t)srow * 512 + k0 + scol);
    const bf16x8 bv1 = *(const bf16x8*)(Wf + (size_t)srow * 512 + k0 + scol + 8);
    *(bf16x8*)(&As[srow * 40 + scol]) = av0;
    *(bf16x8*)(&As[srow * 40 + scol + 8]) = av1;
    *(bf16x8*)(&Bs[srow * 40 + scol]) = bv0;
    *(bf16x8*)(&Bs[srow * 40 + scol + 8]) = bv1;
    __syncthreads();
    bf16x8 af[4], bfg[4];
#pragma unroll
    for (int t = 0; t < 4; ++t) {
      af[t]  = *(const bf16x8*)(&As[(wm + t * 16 + c) * 40 + g * 8]);
      bfg[t] = *(const bf16x8*)(&Bs[(wn + t * 16 + c) * 40 + g * 8]);
    }
#pragma unroll
    for (int rt = 0; rt < 4; ++rt)
#pragma unroll
      for (int ct = 0; ct < 4; ++ct)
        acc[rt][ct] = MFMA_BF16(af[rt], bfg[ct], acc[rt][ct]);
    __syncthreads();
  }

#pragma unroll
  for (int ct = 0; ct < 4; ++ct) {
    const int col = wn + ct * 16 + c;  // 0..127
    const float bj = bfo[col];
#pragma unroll
    for (int rt = 0; rt < 4; ++rt) {
      const int row = m0 + wm + rt * 16 + g * 4;
#pragma unroll
      for (int r = 0; r < 4; ++r) {
        const float vl = (validw[row + r] > 0.5f) ? (acc[rt][ct][r] + bj) : 0.f;
        topic[(size_t)(row + r) * 128 + col] = vl;
      }
    }
  }
}

extern "C" void kernel_launch(void* const* d_in, const int* in_sizes, int n_in,
                              void* d_out, int out_size, void* d_ws, size_t ws_size,
                              hipStream_t stream) {
  const float* a_z  = (const float*)d_in[0];
  const float* bv_z = (const float*)d_in[1];
  const int*   mask = (const int*)d_in[2];
  const float* wgt  = (const float*)d_in[3];
  const float* ipw  = (const float*)d_in[4];
  const float* ipb  = (const float*)d_in[5];
  const float* ow   = (const float*)d_in[6];
  const float* ob   = (const float*)d_in[7];
  float* topic = (float*)d_out;              // [4096 x 128]
  float* infl  = (float*)d_out + 4096 * 128; // [4096]

  char* ws = (char*)d_ws;
  short* Qb     = (short*)(ws);                              // 4 MB
  short* Kb     = (short*)(ws + ((size_t)4 << 20));          // 4 MB
  short* Vt     = (short*)(ws + ((size_t)8 << 20));          // 4 MB  [512][4096]
  short* ctxb   = (short*)(ws + ((size_t)12 << 20));         // 4 MB
  float* validw = (float*)(ws + ((size_t)16 << 20));         // 16 KB
  short* Wf     = (short*)(ws + ((size_t)16 << 20) + (64 << 10));   // 128 KB
  float* bfo    = (float*)(ws + ((size_t)16 << 20) + (224 << 10));  // 512 B

  k_qkv <<<384, 256, 0, stream>>>(a_z, bv_z, ipw, ipb, Qb, Kb, Vt);
  k_fold<<<256, 256, 0, stream>>>(ow, ob, Wf, bfo);
  k_attn<<<128, 256, 0, stream>>>(Qb, Kb, Vt, wgt, mask, ctxb, validw, infl);
  k_out <<<32, 256, 0, stream>>>(ctxb, Wf, bfo, validw, topic);
}

// Round 2
// 715.904 us; speedup vs baseline: 1.7415x; 1.7415x over previous
//
#include <hip/hip_runtime.h>
#include <hip/hip_bf16.h>
#include <cstdint>
#include <cstddef>

// ActorHead fused pipeline, bf16 MFMA throughout.
//   K1 k_qkv : [4096x1536x512] GEMM-BT -> Qb (scaled), Kb, Vt (per-head transposed), all bf16
//   K2 k_attn: split-K flash attention, NO max-subtraction (scores bounded ~7, fp32-safe;
//              masked -> exp(-1e9)=0 exactly). Partials: O/l (bf16), l, lb, ci (fp32).
//   K2b k_comb: merge splits (convex combo of normalized O partials), influence, valid
//   K3 k_fold: fold out_w over heads (topic = ctx @ mean_h(out_w chunks)^T)
//   K4 k_out : [4096x128x512] GEMM -> topic (valid-gated)
// d_out = topic[4096*128] fp32 ++ influence[4096] fp32

typedef __attribute__((ext_vector_type(8))) short bf16x8;
typedef __attribute__((ext_vector_type(4))) short bf16x4;
typedef __attribute__((ext_vector_type(4))) float f32x4;

#define MFMA_BF16(a, b, c) __builtin_amdgcn_mfma_f32_16x16x32_bf16((a), (b), (c), 0, 0, 0)

static __device__ __forceinline__ short f2b(float x) {
  union { float f; unsigned u; } v; v.f = x;
  unsigned r = v.u + 0x7fffu + ((v.u >> 16) & 1u);  // RNE to bf16
  return (short)(r >> 16);
}
static __device__ __forceinline__ float b2f(short s) {
  union { unsigned u; float f; } v; v.u = ((unsigned)(unsigned short)s) << 16;
  return v.f;
}

// ---------------- K1: QKV projection ----------------
__global__ __launch_bounds__(256) void k_qkv(
    const float* __restrict__ a, const float* __restrict__ kv,
    const float* __restrict__ w, const float* __restrict__ bias,
    short* __restrict__ Qb, short* __restrict__ Kb, short* __restrict__ Vt)
{
  __shared__ short As[128 * 40];
  __shared__ short Bs[128 * 40];
  const int blk = blockIdx.x;
  const int bm = blk / 12, bn = blk % 12;
  const int m0 = bm * 128, n0 = bn * 128;
  const float* __restrict__ Ain = (bn < 4) ? a : kv;
  const int tid = threadIdx.x;
  const int lane = tid & 63, wv = tid >> 6;
  const int wm = (wv >> 1) * 64, wn = (wv & 1) * 64;
  const int c = lane & 15, g = lane >> 4;
  const int srow = tid >> 1, scol = (tid & 1) * 16;

  f32x4 acc[4][4];
#pragma unroll
  for (int i = 0; i < 4; ++i)
#pragma unroll
    for (int j = 0; j < 4; ++j) acc[i][j] = (f32x4)0.f;

  for (int k0 = 0; k0 < 512; k0 += 32) {
    const float* ap = Ain + (size_t)(m0 + srow) * 512 + k0 + scol;
    const float* bp = w + (size_t)(n0 + srow) * 512 + k0 + scol;
#pragma unroll
    for (int j = 0; j < 4; ++j) {
      f32x4 av = *(const f32x4*)(ap + 4 * j);
      f32x4 bv = *(const f32x4*)(bp + 4 * j);
      bf16x4 as, bs;
      as.x = f2b(av.x); as.y = f2b(av.y); as.z = f2b(av.z); as.w = f2b(av.w);
      bs.x = f2b(bv.x); bs.y = f2b(bv.y); bs.z = f2b(bv.z); bs.w = f2b(bv.w);
      *(bf16x4*)(&As[srow * 40 + scol + 4 * j]) = as;
      *(bf16x4*)(&Bs[srow * 40 + scol + 4 * j]) = bs;
    }
    __syncthreads();
    bf16x8 af[4], bfg[4];
#pragma unroll
    for (int t = 0; t < 4; ++t) {
      af[t]  = *(const bf16x8*)(&As[(wm + t * 16 + c) * 40 + g * 8]);
      bfg[t] = *(const bf16x8*)(&Bs[(wn + t * 16 + c) * 40 + g * 8]);
    }
#pragma unroll
    for (int rt = 0; rt < 4; ++rt)
#pragma unroll
      for (int ct = 0; ct < 4; ++ct)
        acc[rt][ct] = MFMA_BF16(af[rt], bfg[ct], acc[rt][ct]);
    __syncthreads();
  }

#pragma unroll
  for (int ct = 0; ct < 4; ++ct) {
    const int col = n0 + wn + ct * 16 + c;
    const float bj = bias[col];
#pragma unroll
    for (int rt = 0; rt < 4; ++rt) {
      const int row = m0 + wm + rt * 16 + g * 4;
      if (bn < 4) {
#pragma unroll
        for (int r = 0; r < 4; ++r)
          Qb[(size_t)(row + r) * 512 + col] = f2b((acc[rt][ct][r] + bj) * 0.08838834764831843f);
      } else if (bn < 8) {
#pragma unroll
        for (int r = 0; r < 4; ++r)
          Kb[(size_t)(row + r) * 512 + (col - 512)] = f2b(acc[rt][ct][r] + bj);
      } else {
        bf16x4 pk;
#pragma unroll
        for (int r = 0; r < 4; ++r) pk[r] = f2b(acc[rt][ct][r] + bj);
        *(bf16x4*)(&Vt[(size_t)(col - 1024) * 4096 + row]) = pk;
      }
    }
  }
}

// ---------------- K2: split-K flash attention (no max-subtraction) ----------------
// wg = (row-block of 32) x (key-split of 4096/S). wave = head.
__global__ __launch_bounds__(256) void k_attn(
    const short* __restrict__ Qb, const short* __restrict__ Kb,
    const short* __restrict__ Vt, const float* __restrict__ wgt,
    const int* __restrict__ msk, const int S,
    short* __restrict__ Opart, float* __restrict__ lpart,
    float* __restrict__ cipart, float* __restrict__ lbpart)
{
  __shared__ short Pbuf[4][32 * 72];
  const int bx = blockIdx.x;
  const int rb = bx / S, sp = bx % S;
  const int n0 = rb * 32;
  const int mlen = 4096 / S;
  const int mbase = sp * mlen;
  const int tid = threadIdx.x;
  const int lane = tid & 63, h = tid >> 6;
  const int c = lane & 15, g = lane >> 4;

  bf16x8 qf[2][4];
#pragma unroll
  for (int nb = 0; nb < 2; ++nb)
#pragma unroll
    for (int ks = 0; ks < 4; ++ks)
      qf[nb][ks] = *(const bf16x8*)(Qb + (size_t)(n0 + nb * 16 + c) * 512 + h * 128 + ks * 32 + g * 8);

  f32x4 O[2][8];
#pragma unroll
  for (int nb = 0; nb < 2; ++nb)
#pragma unroll
    for (int db = 0; db < 8; ++db) O[nb][db] = (f32x4)0.f;

  float lh[2][4], lb_[2][4], ci[2][4];
#pragma unroll
  for (int nb = 0; nb < 2; ++nb)
#pragma unroll
    for (int r = 0; r < 4; ++r) { lh[nb][r] = 0.f; lb_[nb][r] = 0.f; ci[nb][r] = 0.f; }

  for (int mt = 0; mt < mlen; mt += 64) {
    const int m0 = mbase + mt;
    // ---- scores S = q @ k^T (C-layout: row=n=g*4+reg, col=m=c) ----
    f32x4 Sv[2][4];
#pragma unroll
    for (int mb = 0; mb < 4; ++mb) {
      bf16x8 kf[4];
#pragma unroll
      for (int ks = 0; ks < 4; ++ks)
        kf[ks] = *(const bf16x8*)(Kb + (size_t)(m0 + mb * 16 + c) * 512 + h * 128 + ks * 32 + g * 8);
#pragma unroll
      for (int nb = 0; nb < 2; ++nb) {
        f32x4 s = (f32x4)0.f;
#pragma unroll
        for (int ks = 0; ks < 4; ++ks) s = MFMA_BF16(qf[nb][ks], kf[ks], s);
        Sv[nb][mb] = s;
      }
    }
    // ---- bias + exp + accumulate + Pbuf (p = exp(qk + b); b=-1e9 -> p=0 exactly) ----
#pragma unroll
    for (int nb = 0; nb < 2; ++nb) {
      const int rbase = n0 + nb * 16 + g * 4;
#pragma unroll
      for (int mb = 0; mb < 4; ++mb) {
        const int colm = m0 + mb * 16 + c;
#pragma unroll
        for (int r = 0; r < 4; ++r) {
          const size_t idx = (size_t)(rbase + r) * 4096 + colm;
          const int mk = msk[idx];
          const float bv = mk ? wgt[idx] : -1e9f;
          const float eb = __expf(bv);
          const float p  = __expf(Sv[nb][mb][r] + bv);
          lh[nb][r] += p; lb_[nb][r] += eb; ci[nb][r] += p * eb;
          Pbuf[h][(nb * 16 + g * 4 + r) * 72 + mb * 16 + c] = f2b(p);
        }
      }
    }
    // ---- PV: O += P @ V ----
#pragma unroll
    for (int ks2 = 0; ks2 < 2; ++ks2) {
      bf16x8 pa[2];
#pragma unroll
      for (int nb = 0; nb < 2; ++nb)
        pa[nb] = *(const bf16x8*)(&Pbuf[h][(nb * 16 + c) * 72 + ks2 * 32 + g * 8]);
#pragma unroll
      for (int db = 0; db < 8; ++db) {
        const bf16x8 vf = *(const bf16x8*)(Vt + (size_t)(h * 128 + db * 16 + c) * 4096 + m0 + ks2 * 32 + g * 8);
#pragma unroll
        for (int nb = 0; nb < 2; ++nb) O[nb][db] = MFMA_BF16(pa[nb], vf, O[nb][db]);
      }
    }
  }

  // ---- cross-lane sums (cols disjoint across the 16 c-lanes) ----
#pragma unroll
  for (int x = 1; x < 16; x <<= 1)
#pragma unroll
    for (int nb = 0; nb < 2; ++nb)
#pragma unroll
      for (int r = 0; r < 4; ++r) {
        lh[nb][r] += __shfl_xor(lh[nb][r], x, 64);
        lb_[nb][r] += __shfl_xor(lb_[nb][r], x, 64);
        ci[nb][r] += __shfl_xor(ci[nb][r], x, 64);
      }

  // ---- normalized O partial (convex-combo-safe in bf16) ----
#pragma unroll
  for (int nb = 0; nb < 2; ++nb)
#pragma unroll
    for (int db = 0; db < 8; ++db)
#pragma unroll
      for (int r = 0; r < 4; ++r) {
        const float o = O[nb][db][r] / fmaxf(lh[nb][r], 1e-30f);
        Opart[(size_t)sp * (4096 * 512) + (size_t)(n0 + nb * 16 + g * 4 + r) * 512 +
              h * 128 + db * 16 + c] = f2b(o);
      }

  if (c == 0) {
#pragma unroll
    for (int nb = 0; nb < 2; ++nb)
#pragma unroll
      for (int r = 0; r < 4; ++r) {
        const int row = n0 + nb * 16 + g * 4 + r;
        lpart[((size_t)sp * 4 + h) * 4096 + row] = lh[nb][r];
        cipart[((size_t)sp * 4 + h) * 4096 + row] = ci[nb][r];
        if (h == 0) lbpart[(size_t)sp * 4096 + row] = lb_[nb][r];
      }
  }
}

// ---------------- K2b: combine splits ----------------
// block = 256 thr = 8 rows x 32 col-segments (16 cols each). grid = 512.
__global__ __launch_bounds__(256) void k_comb(
    const short* __restrict__ Opart, const float* __restrict__ lpart,
    const float* __restrict__ cipart, const float* __restrict__ lbpart,
    const int S, short* __restrict__ ctxb, float* __restrict__ validw,
    float* __restrict__ infl)
{
  const int tid = threadIdx.x;
  const int rloc = tid >> 5, cseg = tid & 31;
  const int row = blockIdx.x * 8 + rloc;
  const int col0 = cseg * 16;
  const int h = col0 >> 7;

  float l[4], ciS[4], lb = 0.f;
#pragma unroll
  for (int hh = 0; hh < 4; ++hh) { l[hh] = 0.f; ciS[hh] = 0.f; }
  for (int s = 0; s < S; ++s) {
#pragma unroll
    for (int hh = 0; hh < 4; ++hh) {
      l[hh]   += lpart[((size_t)s * 4 + hh) * 4096 + row];
      ciS[hh] += cipart[((size_t)s * 4 + hh) * 4096 + row];
    }
    lb += lbpart[(size_t)s * 4096 + row];
  }

  float acc[16];
#pragma unroll
  for (int j = 0; j < 16; ++j) acc[j] = 0.f;
  const float linv = 1.f / fmaxf(l[h], 1e-30f);
  for (int s = 0; s < S; ++s) {
    const float w_s = lpart[((size_t)s * 4 + h) * 4096 + row] * linv;
    const bf16x8 o0 = *(const bf16x8*)(Opart + (size_t)s * (4096 * 512) + (size_t)row * 512 + col0);
    const bf16x8 o1 = *(const bf16x8*)(Opart + (size_t)s * (4096 * 512) + (size_t)row * 512 + col0 + 8);
#pragma unroll
    for (int j = 0; j < 8; ++j) {
      acc[j]     += w_s * b2f(o0[j]);
      acc[8 + j] += w_s * b2f(o1[j]);
    }
  }
  bf16x8 c0, c1;
#pragma unroll
  for (int j = 0; j < 8; ++j) { c0[j] = f2b(acc[j]); c1[j] = f2b(acc[8 + j]); }
  *(bf16x8*)(ctxb + (size_t)row * 512 + col0) = c0;
  *(bf16x8*)(ctxb + (size_t)row * 512 + col0 + 8) = c1;

  if (cseg == 0) {
    const float va = (lb > 0.f) ? 1.f : 0.f;
    validw[row] = va;
    float s_ = 0.f;
#pragma unroll
    for (int hh = 0; hh < 4; ++hh) s_ += ciS[hh] / fmaxf(l[hh], 1e-30f);
    infl[row] = (lb > 0.f) ? s_ / (4.f * lb) : 0.f;
  }
}

// ---------------- K3: fold out_w over heads ----------------
__global__ void k_fold(const float* __restrict__ ow, const float* __restrict__ ob,
                       short* __restrict__ Wf, float* __restrict__ bfo)
{
  const int idx = blockIdx.x * 256 + threadIdx.x;
  if (idx < 128 * 512) {
    const int dk = idx >> 9, d = idx & 511;
    const float s = 0.25f * (ow[(size_t)dk * 512 + d] + ow[(size_t)(dk + 128) * 512 + d] +
                             ow[(size_t)(dk + 256) * 512 + d] + ow[(size_t)(dk + 384) * 512 + d]);
    Wf[(size_t)dk * 512 + d] = f2b(s);
  }
  if (idx < 128) bfo[idx] = 0.25f * (ob[idx] + ob[idx + 128] + ob[idx + 256] + ob[idx + 384]);
}

// ---------------- K4: topic = ctx @ Wfold^T + bfold, valid-gated ----------------
__global__ __launch_bounds__(256) void k_out(
    const short* __restrict__ ctxb, const short* __restrict__ Wf,
    const float* __restrict__ bfo, const float* __restrict__ validw,
    float* __restrict__ topic)
{
  __shared__ short As[128 * 40];
  __shared__ short Bs[128 * 40];
  const int m0 = blockIdx.x * 128;
  const int tid = threadIdx.x;
  const int lane = tid & 63, wv = tid >> 6;
  const int wm = (wv >> 1) * 64, wn = (wv & 1) * 64;
  const int c = lane & 15, g = lane >> 4;
  const int srow = tid >> 1, scol = (tid & 1) * 16;

  f32x4 acc[4][4];
#pragma unroll
  for (int i = 0; i < 4; ++i)
#pragma unroll
    for (int j = 0; j < 4; ++j) acc[i][j] = (f32x4)0.f;

  for (int k0 = 0; k0 < 512; k0 += 32) {
    const bf16x8 av0 = *(const bf16x8*)(ctxb + (size_t)(m0 + srow) * 512 + k0 + scol);
    const bf16x8 av1 = *(const bf16x8*)(ctxb + (size_t)(m0 + srow) * 512 + k0 + scol + 8);
    const bf16x8 bv0 = *(const bf16x8*)(Wf + (size_t)srow * 512 + k0 + scol);
    const bf16x8 bv1 = *(const bf16x8*)(Wf + (size_t)srow * 512 + k0 + scol + 8);
    *(bf16x8*)(&As[srow * 40 + scol]) = av0;
    *(bf16x8*)(&As[srow * 40 + scol + 8]) = av1;
    *(bf16x8*)(&Bs[srow * 40 + scol]) = bv0;
    *(bf16x8*)(&Bs[srow * 40 + scol + 8]) = bv1;
    __syncthreads();
    bf16x8 af[4], bfg[4];
#pragma unroll
    for (int t = 0; t < 4; ++t) {
      af[t]  = *(const bf16x8*)(&As[(wm + t * 16 + c) * 40 + g * 8]);
      bfg[t] = *(const bf16x8*)(&Bs[(wn + t * 16 + c) * 40 + g * 8]);
    }
#pragma unroll
    for (int rt = 0; rt < 4; ++rt)
#pragma unroll
      for (int ct = 0; ct < 4; ++ct)
        acc[rt][ct] = MFMA_BF16(af[rt], bfg[ct], acc[rt][ct]);
    __syncthreads();
  }

#pragma unroll
  for (int ct = 0; ct < 4; ++ct) {
    const int col = wn + ct * 16 + c;
    const float bj = bfo[col];
#pragma unroll
    for (int rt = 0; rt < 4; ++rt) {
      const int row = m0 + wm + rt * 16 + g * 4;
#pragma unroll
      for (int r = 0; r < 4; ++r) {
        const float vl = (validw[row + r] > 0.5f) ? (acc[rt][ct][r] + bj) : 0.f;
        topic[(size_t)(row + r) * 128 + col] = vl;
      }
    }
  }
}

extern "C" void kernel_launch(void* const* d_in, const int* in_sizes, int n_in,
                              void* d_out, int out_size, void* d_ws, size_t ws_size,
                              hipStream_t stream) {
  const float* a_z  = (const float*)d_in[0];
  const float* bv_z = (const float*)d_in[1];
  const int*   mask = (const int*)d_in[2];
  const float* wgt  = (const float*)d_in[3];
  const float* ipw  = (const float*)d_in[4];
  const float* ipb  = (const float*)d_in[5];
  const float* ow   = (const float*)d_in[6];
  const float* ob   = (const float*)d_in[7];
  float* topic = (float*)d_out;              // [4096 x 128]
  float* infl  = (float*)d_out + 4096 * 128; // [4096]

  char* ws = (char*)d_ws;
  short* Qb     = (short*)(ws);                              // 4 MB
  short* Kb     = (short*)(ws + ((size_t)4 << 20));          // 4 MB
  short* Vt     = (short*)(ws + ((size_t)8 << 20));          // 4 MB  [512][4096]
  short* ctxb   = (short*)(ws + ((size_t)12 << 20));         // 4 MB
  float* validw = (float*)(ws + ((size_t)16 << 20));         // 16 KB
  short* Wf     = (short*)(ws + ((size_t)16 << 20) + (64 << 10));   // 128 KB
  float* bfo    = (float*)(ws + ((size_t)16 << 20) + (224 << 10));  // 512 B

  // split-K partial buffers after 17 MB; pick largest S that fits.
  const size_t base = (size_t)17 << 20;
  auto need = [](int S) {
    return ((size_t)17 << 20) +
           (size_t)S * (4096 * 512 * 2)      // Opart bf16
         + (size_t)S * (4 * 4096 * 4) * 2    // lpart + cipart
         + (size_t)S * (4096 * 4);           // lbpart
  };
  int S = 8;
  while (S > 1 && need(S) > ws_size) S >>= 1;
  short* Opart  = (short*)(ws + base);
  float* lpart  = (float*)(ws + base + (size_t)S * (4096 * 512 * 2));
  float* cipart = (float*)(ws + base + (size_t)S * (4096 * 512 * 2) + (size_t)S * (4 * 4096 * 4));
  float* lbpart = (float*)(ws + base + (size_t)S * (4096 * 512 * 2) + (size_t)S * (4 * 4096 * 4) * 2);

  k_qkv <<<384, 256, 0, stream>>>(a_z, bv_z, ipw, ipb, Qb, Kb, Vt);
  k_fold<<<256, 256, 0, stream>>>(ow, ob, Wf, bfo);
  k_attn<<<128 * S, 256, 0, stream>>>(Qb, Kb, Vt, wgt, mask, S, Opart, lpart, cipart, lbpart);
  k_comb<<<512, 256, 0, stream>>>(Opart, lpart, cipart, lbpart, S, ctxb, validw, infl);
  k_out <<<32, 256, 0, stream>>>(ctxb, Wf, bfo, validw, topic);
}

// Round 3
// 376.680 us; speedup vs baseline: 3.3098x; 1.9006x over previous
//
#include <hip/hip_runtime.h>
#include <hip/hip_bf16.h>
#include <cstdint>
#include <cstddef>

// ActorHead fused pipeline, bf16 MFMA throughout.
//   K0 k_bias: eb[4096x4096] = mask ? exp(weight) : 0   (fp32 or bf16, ws-dependent)
//   K1 k_qkv : [4096x1536x512] GEMM-BT -> Qb (scaled), Kb, Vt (per-head transposed)
//   K2 k_attn: split-K flash attention, p = exp(qk)*eb (no max-subtraction; scores bounded).
//              eb tile staged LDS-cooperatively (shared by all 4 head-waves) + 1-tile prefetch.
//   K2b k_comb: merge splits (convex combo of normalized O partials), influence, valid
//   K3 k_fold: fold out_w over heads; K4 k_out: [4096x128x512] GEMM -> topic
// d_out = topic[4096*128] fp32 ++ influence[4096] fp32

typedef __attribute__((ext_vector_type(8))) short bf16x8;
typedef __attribute__((ext_vector_type(4))) short bf16x4;
typedef __attribute__((ext_vector_type(4))) float f32x4;

#define MFMA_BF16(a, b, c) __builtin_amdgcn_mfma_f32_16x16x32_bf16((a), (b), (c), 0, 0, 0)

static __device__ __forceinline__ short f2b(float x) {
  union { float f; unsigned u; } v; v.f = x;
  unsigned r = v.u + 0x7fffu + ((v.u >> 16) & 1u);  // RNE to bf16
  return (short)(r >> 16);
}
static __device__ __forceinline__ float b2f(short s) {
  union { unsigned u; float f; } v; v.u = ((unsigned)(unsigned short)s) << 16;
  return v.f;
}

// ---------------- K0: eb = mask ? exp(w) : 0 ----------------
__global__ __launch_bounds__(256) void k_bias(
    const int4* __restrict__ msk, const float4* __restrict__ wgt,
    float* __restrict__ ebf, short* __restrict__ ebh, const int ebis32)
{
  const int i = blockIdx.x * 256 + threadIdx.x;  // 4 elems per thread
  const int4 m = msk[i];
  const float4 w = wgt[i];
  float4 e;
  e.x = m.x ? __expf(w.x) : 0.f;
  e.y = m.y ? __expf(w.y) : 0.f;
  e.z = m.z ? __expf(w.z) : 0.f;
  e.w = m.w ? __expf(w.w) : 0.f;
  if (ebis32) {
    ((float4*)ebf)[i] = e;
  } else {
    bf16x4 p;
    p.x = f2b(e.x); p.y = f2b(e.y); p.z = f2b(e.z); p.w = f2b(e.w);
    *(bf16x4*)(ebh + (size_t)i * 4) = p;
  }
}

// ---------------- K1: QKV projection ----------------
__global__ __launch_bounds__(256) void k_qkv(
    const float* __restrict__ a, const float* __restrict__ kv,
    const float* __restrict__ w, const float* __restrict__ bias,
    short* __restrict__ Qb, short* __restrict__ Kb, short* __restrict__ Vt)
{
  __shared__ short As[128 * 40];
  __shared__ short Bs[128 * 40];
  const int blk = blockIdx.x;
  const int bm = blk / 12, bn = blk % 12;
  const int m0 = bm * 128, n0 = bn * 128;
  const float* __restrict__ Ain = (bn < 4) ? a : kv;
  const int tid = threadIdx.x;
  const int lane = tid & 63, wv = tid >> 6;
  const int wm = (wv >> 1) * 64, wn = (wv & 1) * 64;
  const int c = lane & 15, g = lane >> 4;
  const int srow = tid >> 1, scol = (tid & 1) * 16;

  f32x4 acc[4][4];
#pragma unroll
  for (int i = 0; i < 4; ++i)
#pragma unroll
    for (int j = 0; j < 4; ++j) acc[i][j] = (f32x4)0.f;

  for (int k0 = 0; k0 < 512; k0 += 32) {
    const float* ap = Ain + (size_t)(m0 + srow) * 512 + k0 + scol;
    const float* bp = w + (size_t)(n0 + srow) * 512 + k0 + scol;
#pragma unroll
    for (int j = 0; j < 4; ++j) {
      f32x4 av = *(const f32x4*)(ap + 4 * j);
      f32x4 bv = *(const f32x4*)(bp + 4 * j);
      bf16x4 as, bs;
      as.x = f2b(av.x); as.y = f2b(av.y); as.z = f2b(av.z); as.w = f2b(av.w);
      bs.x = f2b(bv.x); bs.y = f2b(bv.y); bs.z = f2b(bv.z); bs.w = f2b(bv.w);
      *(bf16x4*)(&As[srow * 40 + scol + 4 * j]) = as;
      *(bf16x4*)(&Bs[srow * 40 + scol + 4 * j]) = bs;
    }
    __syncthreads();
    bf16x8 af[4], bfg[4];
#pragma unroll
    for (int t = 0; t < 4; ++t) {
      af[t]  = *(const bf16x8*)(&As[(wm + t * 16 + c) * 40 + g * 8]);
      bfg[t] = *(const bf16x8*)(&Bs[(wn + t * 16 + c) * 40 + g * 8]);
    }
#pragma unroll
    for (int rt = 0; rt < 4; ++rt)
#pragma unroll
      for (int ct = 0; ct < 4; ++ct)
        acc[rt][ct] = MFMA_BF16(af[rt], bfg[ct], acc[rt][ct]);
    __syncthreads();
  }

#pragma unroll
  for (int ct = 0; ct < 4; ++ct) {
    const int col = n0 + wn + ct * 16 + c;
    const float bj = bias[col];
#pragma unroll
    for (int rt = 0; rt < 4; ++rt) {
      const int row = m0 + wm + rt * 16 + g * 4;
      if (bn < 4) {
#pragma unroll
        for (int r = 0; r < 4; ++r)
          Qb[(size_t)(row + r) * 512 + col] = f2b((acc[rt][ct][r] + bj) * 0.08838834764831843f);
      } else if (bn < 8) {
#pragma unroll
        for (int r = 0; r < 4; ++r)
          Kb[(size_t)(row + r) * 512 + (col - 512)] = f2b(acc[rt][ct][r] + bj);
      } else {
        bf16x4 pk;
#pragma unroll
        for (int r = 0; r < 4; ++r) pk[r] = f2b(acc[rt][ct][r] + bj);
        *(bf16x4*)(&Vt[(size_t)(col - 1024) * 4096 + row]) = pk;
      }
    }
  }
}

// ---------------- K2: split-K flash attention (eb-staged, no max-subtraction) ----------------
// wg = (row-block of 32) x (key-split of 4096/S). wave = head.
__global__ __launch_bounds__(256) void k_attn(
    const short* __restrict__ Qb, const short* __restrict__ Kb,
    const short* __restrict__ Vt, const float* __restrict__ ebf,
    const short* __restrict__ ebh, const int ebis32, const int S,
    short* __restrict__ Opart, float* __restrict__ lpart,
    float* __restrict__ cipart, float* __restrict__ lbpart)
{
  __shared__ float Et[64][36];        // [col][row(+pad->36)] fp32; 16B-aligned b128 reads
  __shared__ short Pbuf[4][32 * 72];  // per-wave P round-trip (C-layout -> A-layout)
  const int bx = blockIdx.x;
  const int rb = bx / S, sp = bx % S;
  const int n0 = rb * 32;
  const int mlen = 4096 / S;
  const int mbase = sp * mlen;
  const int ntiles = mlen >> 6;
  const int tid = threadIdx.x;
  const int lane = tid & 63, h = tid >> 6;
  const int c = lane & 15, g = lane >> 4;
  const int ldr = tid >> 3, ldc = (tid & 7) * 8;  // cooperative eb loader: row, col0

  bf16x8 qf[2][4];
#pragma unroll
  for (int nb = 0; nb < 2; ++nb)
#pragma unroll
    for (int ks = 0; ks < 4; ++ks)
      qf[nb][ks] = *(const bf16x8*)(Qb + (size_t)(n0 + nb * 16 + c) * 512 + h * 128 + ks * 32 + g * 8);

  f32x4 O[2][8];
#pragma unroll
  for (int nb = 0; nb < 2; ++nb)
#pragma unroll
    for (int db = 0; db < 8; ++db) O[nb][db] = (f32x4)0.f;

  float lh[2][4], lb_[2][4], ci[2][4];
#pragma unroll
  for (int nb = 0; nb < 2; ++nb)
#pragma unroll
    for (int r = 0; r < 4; ++r) { lh[nb][r] = 0.f; lb_[nb][r] = 0.f; ci[nb][r] = 0.f; }

  // prefetch eb tile 0 into regs
  float pf[8];
  {
    const size_t off = (size_t)(n0 + ldr) * 4096 + mbase + ldc;
    if (ebis32) {
      f32x4 x = *(const f32x4*)(ebf + off);
      f32x4 y = *(const f32x4*)(ebf + off + 4);
      pf[0] = x.x; pf[1] = x.y; pf[2] = x.z; pf[3] = x.w;
      pf[4] = y.x; pf[5] = y.y; pf[6] = y.z; pf[7] = y.w;
    } else {
      bf16x8 v = *(const bf16x8*)(ebh + off);
#pragma unroll
      for (int j = 0; j < 8; ++j) pf[j] = b2f(v[j]);
    }
  }

  for (int it = 0; it < ntiles; ++it) {
    const int m0 = mbase + it * 64;
    __syncthreads();  // Et free (previous tile's compute done)
#pragma unroll
    for (int j = 0; j < 8; ++j) Et[ldc + j][ldr] = pf[j];
    if (it + 1 < ntiles) {  // issue next tile's global load early (overlaps compute)
      const size_t off = (size_t)(n0 + ldr) * 4096 + mbase + (it + 1) * 64 + ldc;
      if (ebis32) {
        f32x4 x = *(const f32x4*)(ebf + off);
        f32x4 y = *(const f32x4*)(ebf + off + 4);
        pf[0] = x.x; pf[1] = x.y; pf[2] = x.z; pf[3] = x.w;
        pf[4] = y.x; pf[5] = y.y; pf[6] = y.z; pf[7] = y.w;
      } else {
        bf16x8 v = *(const bf16x8*)(ebh + off);
#pragma unroll
        for (int j = 0; j < 8; ++j) pf[j] = b2f(v[j]);
      }
    }
    __syncthreads();  // Et ready

    // ---- scores S = q @ k^T (C-layout: row=n=g*4+reg, col=m=c) ----
    f32x4 Sv[2][4];
#pragma unroll
    for (int mb = 0; mb < 4; ++mb) {
      bf16x8 kf[4];
#pragma unroll
      for (int ks = 0; ks < 4; ++ks)
        kf[ks] = *(const bf16x8*)(Kb + (size_t)(m0 + mb * 16 + c) * 512 + h * 128 + ks * 32 + g * 8);
#pragma unroll
      for (int nb = 0; nb < 2; ++nb) {
        f32x4 s = (f32x4)0.f;
#pragma unroll
        for (int ks = 0; ks < 4; ++ks) s = MFMA_BF16(qf[nb][ks], kf[ks], s);
        Sv[nb][mb] = s;
      }
    }
    // ---- p = exp(qk) * eb; accumulate l, lb, cross-term; Pbuf ----
#pragma unroll
    for (int nb = 0; nb < 2; ++nb)
#pragma unroll
      for (int mb = 0; mb < 4; ++mb) {
        const f32x4 ebv = *(const f32x4*)(&Et[mb * 16 + c][nb * 16 + g * 4]);
#pragma unroll
        for (int r = 0; r < 4; ++r) {
          const float e = ebv[r];
          const float p = __expf(Sv[nb][mb][r]) * e;  // masked: e=0 -> p=0 exactly
          lh[nb][r] += p; lb_[nb][r] += e; ci[nb][r] += p * e;
          Pbuf[h][(nb * 16 + g * 4 + r) * 72 + mb * 16 + c] = f2b(p);
        }
      }
    // ---- PV: O += P @ V ----
#pragma unroll
    for (int ks2 = 0; ks2 < 2; ++ks2) {
      bf16x8 pa[2];
#pragma unroll
      for (int nb = 0; nb < 2; ++nb)
        pa[nb] = *(const bf16x8*)(&Pbuf[h][(nb * 16 + c) * 72 + ks2 * 32 + g * 8]);
#pragma unroll
      for (int db = 0; db < 8; ++db) {
        const bf16x8 vf = *(const bf16x8*)(Vt + (size_t)(h * 128 + db * 16 + c) * 4096 + m0 + ks2 * 32 + g * 8);
#pragma unroll
        for (int nb = 0; nb < 2; ++nb) O[nb][db] = MFMA_BF16(pa[nb], vf, O[nb][db]);
      }
    }
  }

  // ---- cross-lane sums (cols disjoint across the 16 c-lanes) ----
#pragma unroll
  for (int x = 1; x < 16; x <<= 1)
#pragma unroll
    for (int nb = 0; nb < 2; ++nb)
#pragma unroll
      for (int r = 0; r < 4; ++r) {
        lh[nb][r] += __shfl_xor(lh[nb][r], x, 64);
        lb_[nb][r] += __shfl_xor(lb_[nb][r], x, 64);
        ci[nb][r] += __shfl_xor(ci[nb][r], x, 64);
      }

  // ---- normalized O partial (convex-combo-safe in bf16) ----
#pragma unroll
  for (int nb = 0; nb < 2; ++nb)
#pragma unroll
    for (int db = 0; db < 8; ++db)
#pragma unroll
      for (int r = 0; r < 4; ++r) {
        const float o = O[nb][db][r] / fmaxf(lh[nb][r], 1e-30f);
        Opart[(size_t)sp * (4096 * 512) + (size_t)(n0 + nb * 16 + g * 4 + r) * 512 +
              h * 128 + db * 16 + c] = f2b(o);
      }

  if (c == 0) {
#pragma unroll
    for (int nb = 0; nb < 2; ++nb)
#pragma unroll
      for (int r = 0; r < 4; ++r) {
        const int row = n0 + nb * 16 + g * 4 + r;
        lpart[((size_t)sp * 4 + h) * 4096 + row] = lh[nb][r];
        cipart[((size_t)sp * 4 + h) * 4096 + row] = ci[nb][r];
        if (h == 0) lbpart[(size_t)sp * 4096 + row] = lb_[nb][r];
      }
  }
}

// ---------------- K2b: combine splits ----------------
__global__ __launch_bounds__(256) void k_comb(
    const short* __restrict__ Opart, const float* __restrict__ lpart,
    const float* __restrict__ cipart, const float* __restrict__ lbpart,
    const int S, short* __restrict__ ctxb, float* __restrict__ validw,
    float* __restrict__ infl)
{
  const int tid = threadIdx.x;
  const int rloc = tid >> 5, cseg = tid & 31;
  const int row = blockIdx.x * 8 + rloc;
  const int col0 = cseg * 16;
  const int h = col0 >> 7;

  float l[4], ciS[4], lb = 0.f;
#pragma unroll
  for (int hh = 0; hh < 4; ++hh) { l[hh] = 0.f; ciS[hh] = 0.f; }
  for (int s = 0; s < S; ++s) {
#pragma unroll
    for (int hh = 0; hh < 4; ++hh) {
      l[hh]   += lpart[((size_t)s * 4 + hh) * 4096 + row];
      ciS[hh] += cipart[((size_t)s * 4 + hh) * 4096 + row];
    }
    lb += lbpart[(size_t)s * 4096 + row];
  }

  float acc[16];
#pragma unroll
  for (int j = 0; j < 16; ++j) acc[j] = 0.f;
  const float linv = 1.f / fmaxf(l[h], 1e-30f);
  for (int s = 0; s < S; ++s) {
    const float w_s = lpart[((size_t)s * 4 + h) * 4096 + row] * linv;
    const bf16x8 o0 = *(const bf16x8*)(Opart + (size_t)s * (4096 * 512) + (size_t)row * 512 + col0);
    const bf16x8 o1 = *(const bf16x8*)(Opart + (size_t)s * (4096 * 512) + (size_t)row * 512 + col0 + 8);
#pragma unroll
    for (int j = 0; j < 8; ++j) {
      acc[j]     += w_s * b2f(o0[j]);
      acc[8 + j] += w_s * b2f(o1[j]);
    }
  }
  bf16x8 c0, c1;
#pragma unroll
  for (int j = 0; j < 8; ++j) { c0[j] = f2b(acc[j]); c1[j] = f2b(acc[8 + j]); }
  *(bf16x8*)(ctxb + (size_t)row * 512 + col0) = c0;
  *(bf16x8*)(ctxb + (size_t)row * 512 + col0 + 8) = c1;

  if (cseg == 0) {
    validw[row] = (lb > 0.f) ? 1.f : 0.f;
    float s_ = 0.f;
#pragma unroll
    for (int hh = 0; hh < 4; ++hh) s_ += ciS[hh] / fmaxf(l[hh], 1e-30f);
    infl[row] = (lb > 0.f) ? s_ / (4.f * lb) : 0.f;
  }
}

// ---------------- K3: fold out_w over heads ----------------
__global__ void k_fold(const float* __restrict__ ow, const float* __restrict__ ob,
                       short* __restrict__ Wf, float* __restrict__ bfo)
{
  const int idx = blockIdx.x * 256 + threadIdx.x;
  if (idx < 128 * 512) {
    const int dk = idx >> 9, d = idx & 511;
    const float s = 0.25f * (ow[(size_t)dk * 512 + d] + ow[(size_t)(dk + 128) * 512 + d] +
                             ow[(size_t)(dk + 256) * 512 + d] + ow[(size_t)(dk + 384) * 512 + d]);
    Wf[(size_t)dk * 512 + d] = f2b(s);
  }
  if (idx < 128) bfo[idx] = 0.25f * (ob[idx] + ob[idx + 128] + ob[idx + 256] + ob[idx + 384]);
}

// ---------------- K4: topic = ctx @ Wfold^T + bfold, valid-gated ----------------
__global__ __launch_bounds__(256) void k_out(
    const short* __restrict__ ctxb, const short* __restrict__ Wf,
    const float* __restrict__ bfo, const float* __restrict__ validw,
    float* __restrict__ topic)
{
  __shared__ short As[128 * 40];
  __shared__ short Bs[128 * 40];
  const int m0 = blockIdx.x * 128;
  const int tid = threadIdx.x;
  const int lane = tid & 63, wv = tid >> 6;
  const int wm = (wv >> 1) * 64, wn = (wv & 1) * 64;
  const int c = lane & 15, g = lane >> 4;
  const int srow = tid >> 1, scol = (tid & 1) * 16;

  f32x4 acc[4][4];
#pragma unroll
  for (int i = 0; i < 4; ++i)
#pragma unroll
    for (int j = 0; j < 4; ++j) acc[i][j] = (f32x4)0.f;

  for (int k0 = 0; k0 < 512; k0 += 32) {
    const bf16x8 av0 = *(const bf16x8*)(ctxb + (size_t)(m0 + srow) * 512 + k0 + scol);
    const bf16x8 av1 = *(const bf16x8*)(ctxb + (size_t)(m0 + srow) * 512 + k0 + scol + 8);
    const bf16x8 bv0 = *(const bf16x8*)(Wf + (size_t)srow * 512 + k0 + scol);
    const bf16x8 bv1 = *(const bf16x8*)(Wf + (size_t)srow * 512 + k0 + scol + 8);
    *(bf16x8*)(&As[srow * 40 + scol]) = av0;
    *(bf16x8*)(&As[srow * 40 + scol + 8]) = av1;
    *(bf16x8*)(&Bs[srow * 40 + scol]) = bv0;
    *(bf16x8*)(&Bs[srow * 40 + scol + 8]) = bv1;
    __syncthreads();
    bf16x8 af[4], bfg[4];
#pragma unroll
    for (int t = 0; t < 4; ++t) {
      af[t]  = *(const bf16x8*)(&As[(wm + t * 16 + c) * 40 + g * 8]);
      bfg[t] = *(const bf16x8*)(&Bs[(wn + t * 16 + c) * 40 + g * 8]);
    }
#pragma unroll
    for (int rt = 0; rt < 4; ++rt)
#pragma unroll
      for (int ct = 0; ct < 4; ++ct)
        acc[rt][ct] = MFMA_BF16(af[rt], bfg[ct], acc[rt][ct]);
    __syncthreads();
  }

#pragma unroll
  for (int ct = 0; ct < 4; ++ct) {
    const int col = wn + ct * 16 + c;
    const float bj = bfo[col];
#pragma unroll
    for (int rt = 0; rt < 4; ++rt) {
      const int row = m0 + wm + rt * 16 + g * 4;
#pragma unroll
      for (int r = 0; r < 4; ++r) {
        const float vl = (validw[row + r] > 0.5f) ? (acc[rt][ct][r] + bj) : 0.f;
        topic[(size_t)(row + r) * 128 + col] = vl;
      }
    }
  }
}

extern "C" void kernel_launch(void* const* d_in, const int* in_sizes, int n_in,
                              void* d_out, int out_size, void* d_ws, size_t ws_size,
                              hipStream_t stream) {
  const float* a_z  = (const float*)d_in[0];
  const float* bv_z = (const float*)d_in[1];
  const int*   mask = (const int*)d_in[2];
  const float* wgt  = (const float*)d_in[3];
  const float* ipw  = (const float*)d_in[4];
  const float* ipb  = (const float*)d_in[5];
  const float* ow   = (const float*)d_in[6];
  const float* ob   = (const float*)d_in[7];
  float* topic = (float*)d_out;              // [4096 x 128]
  float* infl  = (float*)d_out + 4096 * 128; // [4096]

  const size_t MB = (size_t)1 << 20;
  char* ws = (char*)d_ws;
  short* Qb     = (short*)(ws);                    // 4 MB
  short* Kb     = (short*)(ws + 4 * MB);           // 4 MB
  short* Vt     = (short*)(ws + 8 * MB);           // 4 MB  [512][4096]
  float* validw = (float*)(ws + 12 * MB);          // 16 KB
  short* Wf     = (short*)(ws + 12 * MB + (64 << 10));   // 128 KB
  float* bfo    = (float*)(ws + 12 * MB + (224 << 10));  // 512 B
  const size_t eb_base = 12 * MB + (256 << 10);    // 12.25 MB

  // part buffers per split: Opart 4MB + lpart 64KB + cipart 64KB + lbpart 16KB
  auto part = [&](int S) { return (size_t)S * (4 * MB + (144 << 10)); };

  int ebis32, S;
  if (eb_base + 64 * MB + part(8) <= ws_size) { ebis32 = 1; S = 8; }
  else {
    ebis32 = 0; S = 8;
    while (S > 1 && eb_base + 32 * MB + part(S) > ws_size) S >>= 1;
  }
  const size_t ebbytes = ebis32 ? 64 * MB : 32 * MB;
  float* ebf = (float*)(ws + eb_base);
  short* ebh = (short*)(ws + eb_base);
  short* ctxb = (short*)(ws + eb_base);  // aliases eb (dead after k_attn)

  char* pbase = ws + eb_base + ebbytes;
  short* Opart  = (short*)(pbase);
  float* lpart  = (float*)(pbase + (size_t)S * 4 * MB);
  float* cipart = (float*)(pbase + (size_t)S * 4 * MB + ((size_t)S << 16));
  float* lbpart = (float*)(pbase + (size_t)S * 4 * MB + ((size_t)S << 17));

  k_bias<<<16384, 256, 0, stream>>>((const int4*)mask, (const float4*)wgt, ebf, ebh, ebis32);
  k_qkv <<<384, 256, 0, stream>>>(a_z, bv_z, ipw, ipb, Qb, Kb, Vt);
  k_fold<<<256, 256, 0, stream>>>(ow, ob, Wf, bfo);
  k_attn<<<128 * S, 256, 0, stream>>>(Qb, Kb, Vt, ebf, ebh, ebis32, S, Opart, lpart, cipart, lbpart);
  k_comb<<<512, 256, 0, stream>>>(Opart, lpart, cipart, lbpart, S, ctxb, validw, infl);
  k_out <<<32, 256, 0, stream>>>(ctxb, Wf, bfo, validw, topic);
}